// Round 7
// baseline (440.885 us; speedup 1.0000x reference)
//
#include <hip/hip_runtime.h>

// Problem constants (fixed by the reference setup_inputs)
#define B_SZ 2
#define T_SZ 2048
#define DM   1024
#define NH   16
#define DH   64
#define MROWS (B_SZ * T_SZ)   // 4096
#define CTX_CH 8              // split-K chunks for the ctx matmul

typedef unsigned short u16;
typedef short  s16x8 __attribute__((ext_vector_type(8)));   // 8 bf16 (4 VGPRs)
typedef float  f32x4 __attribute__((ext_vector_type(4)));   // MFMA C/D

// fp32 -> bf16 round-to-nearest-even
static __device__ __forceinline__ u16 f2bf(float x) {
  unsigned u = __float_as_uint(x);
  u += 0x7fffu + ((u >> 16) & 1u);
  return (u16)(u >> 16);
}

// ---------------------------------------------------------------------------
// Merged q/k fp32->bf16 convert. z=0: q->qb, z=1: k->kb. grid (4096,1,2).
// ---------------------------------------------------------------------------
__global__ __launch_bounds__(256)
void k_cvt2(const float* __restrict__ q, const float* __restrict__ k,
            u16* __restrict__ qb, u16* __restrict__ kb) {
  const float* x = blockIdx.z ? k : q;
  u16* y = blockIdx.z ? kb : qb;
  int i = blockIdx.x * 256 + threadIdx.x;
  float4 v = ((const float4*)x)[i];
  ushort4 o;
  o.x = f2bf(v.x); o.y = f2bf(v.y); o.z = f2bf(v.z); o.w = f2bf(v.w);
  ((ushort4*)y)[i] = o;
}

// ---------------------------------------------------------------------------
// Wt[n][k] = bf16(W[k][n]) for Wq/Wk (z selects). grid (16,16,2).
// ---------------------------------------------------------------------------
__global__ __launch_bounds__(256)
void k_cvt_T2(const float* __restrict__ Wq, const float* __restrict__ Wk,
              u16* __restrict__ Wqt, u16* __restrict__ Wkt) {
  const float* W = blockIdx.z ? Wk : Wq;
  u16* Wt = blockIdx.z ? Wkt : Wqt;
  __shared__ u16 t[64][72];
  const int n0 = blockIdx.x * 64, k0 = blockIdx.y * 64;
  const int tid = threadIdx.x;
#pragma unroll
  for (int e = 0; e < 4; ++e) {
    int c = tid + e * 256;
    int k = c >> 4, n4 = c & 15;
    float4 v = *(const float4*)(W + (size_t)(k0 + k) * DM + n0 + n4 * 4);
    t[n4 * 4 + 0][k] = f2bf(v.x);
    t[n4 * 4 + 1][k] = f2bf(v.y);
    t[n4 * 4 + 2][k] = f2bf(v.z);
    t[n4 * 4 + 3][k] = f2bf(v.w);
  }
  __syncthreads();
#pragma unroll
  for (int e = 0; e < 2; ++e) {
    int c = tid + e * 256;
    int n = c >> 3, c16 = c & 7;
    *(uint4*)(Wt + (size_t)(n0 + n) * DM + k0 + c16 * 8) = *(const uint4*)&t[n][c16 * 8];
  }
}

// ---------------------------------------------------------------------------
// Merged projection GEMM: z=0: Qp = (qb @ Wqt^T)*qscale, z=1: Kp = kb @ Wkt^T.
// 128x128 tile, BK=32, 4 waves 2x2. grid (8,32,2).
// ---------------------------------------------------------------------------
__global__ __launch_bounds__(256)
void gemm_qk(const u16* __restrict__ qb, const u16* __restrict__ kb,
             const u16* __restrict__ Wqt, const u16* __restrict__ Wkt,
             u16* __restrict__ Qp, u16* __restrict__ Kp, float qscale) {
  const int z = blockIdx.z;
  const u16* A  = z ? kb : qb;
  const u16* Bt = z ? Wkt : Wqt;
  u16* C = z ? Kp : Qp;
  const float scale = z ? 1.0f : qscale;

  __shared__ u16 As[128][40];
  __shared__ u16 Bs[128][40];
  const int tid = threadIdx.x;
  const int lane = tid & 63, w = tid >> 6;
  const int l15 = lane & 15, q4 = lane >> 4;
  const int wm = w & 1, wn = w >> 1;
  const int m0 = blockIdx.y * 128, n0 = blockIdx.x * 128;

  f32x4 acc[4][4] = {};

  for (int k0 = 0; k0 < DM; k0 += 32) {
    __syncthreads();
#pragma unroll
    for (int e = 0; e < 2; ++e) {
      int c = tid + e * 256;
      int row = c >> 2, c16 = c & 3;
      *(uint4*)&As[row][c16 * 8] = *(const uint4*)(A  + (size_t)(m0 + row) * DM + k0 + c16 * 8);
      *(uint4*)&Bs[row][c16 * 8] = *(const uint4*)(Bt + (size_t)(n0 + row) * DM + k0 + c16 * 8);
    }
    __syncthreads();
    s16x8 a[4], b[4];
#pragma unroll
    for (int mi = 0; mi < 4; ++mi) a[mi] = *(const s16x8*)&As[wm * 64 + mi * 16 + l15][q4 * 8];
#pragma unroll
    for (int ni = 0; ni < 4; ++ni) b[ni] = *(const s16x8*)&Bs[wn * 64 + ni * 16 + l15][q4 * 8];
#pragma unroll
    for (int mi = 0; mi < 4; ++mi)
#pragma unroll
      for (int ni = 0; ni < 4; ++ni)
        acc[mi][ni] = __builtin_amdgcn_mfma_f32_16x16x32_bf16(a[mi], b[ni], acc[mi][ni], 0, 0, 0);
  }
#pragma unroll
  for (int mi = 0; mi < 4; ++mi)
#pragma unroll
    for (int ni = 0; ni < 4; ++ni)
#pragma unroll
      for (int r = 0; r < 4; ++r) {
        int m = m0 + wm * 64 + mi * 16 + q4 * 4 + r;
        int n = n0 + wn * 64 + ni * 16 + l15;
        C[(size_t)m * DM + n] = f2bf(acc[mi][ni][r] * scale);
      }
}

// ---------------------------------------------------------------------------
// Pass 1 v5: block (qt, h, b), grid 1024. Q frags direct global->regs (no
// LDS, no barrier). Rounds of 256 k-cols: stage K[256][72] with 8-uint4
// register prefetch; 32 MFMAs + 64 exps per wave per round. Writes
// invL = 1/rowsum directly (no atomics). Q pre-scaled by 0.125*log2e.
// ---------------------------------------------------------------------------
__global__ __launch_bounds__(256)
void attn_sums_v5(const u16* __restrict__ Qb, const u16* __restrict__ Kb,
                  float* __restrict__ invL) {
  __shared__ u16 Ks[256][72];
  __shared__ float red[64][17];
  const int qt = blockIdx.x, h = blockIdx.y, b = blockIdx.z;
  const int tid = threadIdx.x;
  const int lane = tid & 63, w = tid >> 6;
  const int l15 = lane & 15, q4 = lane >> 4;

  // Q fragments straight from global (one-time, 16B/lane x2)
  const u16* Qbase = Qb + ((size_t)(b * T_SZ + qt * 64)) * DM + h * DH;
  s16x8 aq0 = *(const s16x8*)(Qbase + (size_t)(w * 16 + l15) * DM + q4 * 8);
  s16x8 aq1 = *(const s16x8*)(Qbase + (size_t)(w * 16 + l15) * DM + 32 + q4 * 8);

  const int R = (qt >> 2) + 1;          // rounds of 256 k-cols
  const u16* Kbase = Kb + ((size_t)b * T_SZ) * DM + h * DH;

  uint4 pf[8];
#pragma unroll
  for (int e = 0; e < 8; ++e) {
    int cc = tid + e * 256;
    int row = cc >> 3, c8 = cc & 7;
    pf[e] = *(const uint4*)(Kbase + (size_t)row * DM + c8 * 8);
  }

  float partial[4] = {0.f, 0.f, 0.f, 0.f};

  for (int r = 0; r < R; ++r) {
    __syncthreads();
#pragma unroll
    for (int e = 0; e < 8; ++e) {
      int cc = tid + e * 256;
      int row = cc >> 3, c8 = cc & 7;
      *(uint4*)&Ks[row][c8 * 8] = pf[e];
    }
    if (r + 1 < R) {
      const u16* Kn = Kbase + (size_t)(r + 1) * 256 * DM;
#pragma unroll
      for (int e = 0; e < 8; ++e) {
        int cc = tid + e * 256;
        int row = cc >> 3, c8 = cc & 7;
        pf[e] = *(const uint4*)(Kn + (size_t)row * DM + c8 * 8);
      }
    }
    __syncthreads();
#pragma unroll
    for (int ni = 0; ni < 16; ++ni) {
      const int ktt = r * 4 + (ni >> 2);
      if (ktt > qt) continue;           // wave-uniform
      s16x8 b0 = *(const s16x8*)&Ks[ni * 16 + l15][q4 * 8];
      s16x8 b1 = *(const s16x8*)&Ks[ni * 16 + l15][32 + q4 * 8];
      f32x4 s = {};
      s = __builtin_amdgcn_mfma_f32_16x16x32_bf16(aq0, b0, s, 0, 0, 0);
      s = __builtin_amdgcn_mfma_f32_16x16x32_bf16(aq1, b1, s, 0, 0, 0);
      if (ktt == qt) {
#pragma unroll
        for (int rr = 0; rr < 4; ++rr) {
          int row_l = w * 16 + q4 * 4 + rr;
          int col_l = (ni & 3) * 16 + l15;
          partial[rr] += (col_l <= row_l) ? __builtin_amdgcn_exp2f(s[rr]) : 0.f;
        }
      } else {
#pragma unroll
        for (int rr = 0; rr < 4; ++rr)
          partial[rr] += __builtin_amdgcn_exp2f(s[rr]);
      }
    }
  }
  __syncthreads();
#pragma unroll
  for (int rr = 0; rr < 4; ++rr) red[w * 16 + q4 * 4 + rr][l15] = partial[rr];
  __syncthreads();
  if (tid < 64) {
    float sum = 0.f;
#pragma unroll
    for (int t = 0; t < 16; ++t) sum += red[tid][t];
    invL[((size_t)(b * NH + h)) * T_SZ + qt * 64 + tid] = 1.0f / sum;
  }
}

// ---------------------------------------------------------------------------
// Pass 2 v5: 64x64 tile per block, grid (32,32,2); upper tiles zero & exit.
// One head per round (16 rounds), LDS 22.5 KB -> ~7 blocks/CU resident;
// 4-uint4 register prefetch of the next head's Q/K slices.
// ---------------------------------------------------------------------------
__global__ __launch_bounds__(256)
void attn_write_v5(const u16* __restrict__ Qb, const u16* __restrict__ Kb,
                   const float* __restrict__ invL, float* __restrict__ attn) {
  const int kt = blockIdx.x, qt = blockIdx.y, b = blockIdx.z;
  const int tid = threadIdx.x;
  float* outp = attn + ((size_t)b * T_SZ + (size_t)qt * 64) * T_SZ + kt * 64;

  if (kt > qt) {
    float4 z = make_float4(0.f, 0.f, 0.f, 0.f);
#pragma unroll
    for (int e = 0; e < 4; ++e) {
      int lin = tid + e * 256;
      int i = lin >> 4, c4 = lin & 15;
      *(float4*)(outp + (size_t)i * T_SZ + c4 * 4) = z;
    }
    return;
  }

  __shared__ u16 Qs[64][72];
  __shared__ u16 Ks[64][72];
  __shared__ float Ls[16][64];
  const int lane = tid & 63, w = tid >> 6;
  const int l15 = lane & 15, q4 = lane >> 4;
  const bool diag = (kt == qt);

  {  // stage invL (already reciprocal) for all 16 heads
    int hh = tid >> 4, r4 = tid & 15;
    *(float4*)&Ls[hh][r4 * 4] =
        *(const float4*)(invL + ((size_t)(b * NH + hh)) * T_SZ + qt * 64 + r4 * 4);
  }

  const u16* Qrow = Qb + ((size_t)(b * T_SZ + qt * 64)) * DM;
  const u16* Krow = Kb + ((size_t)(b * T_SZ + kt * 64)) * DM;

  uint4 pfQ[2], pfK[2];
#pragma unroll
  for (int e = 0; e < 2; ++e) {
    int cc = tid + e * 256;
    int row = cc >> 3, c8 = cc & 7;
    pfQ[e] = *(const uint4*)(Qrow + (size_t)row * DM + c8 * 8);
    pfK[e] = *(const uint4*)(Krow + (size_t)row * DM + c8 * 8);
  }

  f32x4 acc[4] = {};

  for (int h = 0; h < NH; ++h) {
    __syncthreads();
#pragma unroll
    for (int e = 0; e < 2; ++e) {
      int cc = tid + e * 256;
      int row = cc >> 3, c8 = cc & 7;
      *(uint4*)&Qs[row][c8 * 8] = pfQ[e];
      *(uint4*)&Ks[row][c8 * 8] = pfK[e];
    }
    if (h + 1 < NH) {
      const int off = (h + 1) * DH;
#pragma unroll
      for (int e = 0; e < 2; ++e) {
        int cc = tid + e * 256;
        int row = cc >> 3, c8 = cc & 7;
        pfQ[e] = *(const uint4*)(Qrow + (size_t)row * DM + off + c8 * 8);
        pfK[e] = *(const uint4*)(Krow + (size_t)row * DM + off + c8 * 8);
      }
    }
    __syncthreads();
    s16x8 aq0 = *(const s16x8*)&Qs[w * 16 + l15][q4 * 8];
    s16x8 aq1 = *(const s16x8*)&Qs[w * 16 + l15][32 + q4 * 8];
    f32x4 s[4] = {};
#pragma unroll
    for (int ni = 0; ni < 4; ++ni) {
      s16x8 b0 = *(const s16x8*)&Ks[ni * 16 + l15][q4 * 8];
      s16x8 b1 = *(const s16x8*)&Ks[ni * 16 + l15][32 + q4 * 8];
      s[ni] = __builtin_amdgcn_mfma_f32_16x16x32_bf16(aq0, b0, s[ni], 0, 0, 0);
      s[ni] = __builtin_amdgcn_mfma_f32_16x16x32_bf16(aq1, b1, s[ni], 0, 0, 0);
    }
    if (diag) {
#pragma unroll
      for (int ni = 0; ni < 4; ++ni)
#pragma unroll
        for (int r = 0; r < 4; ++r) {
          int row_l = w * 16 + q4 * 4 + r;
          int col_l = ni * 16 + l15;
          float ev = __builtin_amdgcn_exp2f(s[ni][r]) * Ls[h][row_l];
          if (col_l <= row_l) acc[ni][r] += ev;
        }
    } else {
#pragma unroll
      for (int ni = 0; ni < 4; ++ni)
#pragma unroll
        for (int r = 0; r < 4; ++r) {
          int row_l = w * 16 + q4 * 4 + r;
          acc[ni][r] += __builtin_amdgcn_exp2f(s[ni][r]) * Ls[h][row_l];
        }
    }
  }
#pragma unroll
  for (int ni = 0; ni < 4; ++ni)
#pragma unroll
    for (int r = 0; r < 4; ++r)
      outp[(size_t)(w * 16 + q4 * 4 + r) * T_SZ + ni * 16 + l15] = acc[ni][r] * 0.0625f;
}

// ---------------------------------------------------------------------------
// V projection: C[4096][64] = A[4096][1024] @ W[1024][64], fp32. 256 blocks.
// ---------------------------------------------------------------------------
__global__ __launch_bounds__(256)
void proj_v(const float* __restrict__ A, const float* __restrict__ W,
            float* __restrict__ C) {
  __shared__ float Ws[64][68];
  __shared__ float As[16][68];
  const int tid = threadIdx.x;
  const int m0 = blockIdx.x * 16;
  const int row = tid >> 4;
  const int c4  = tid & 15;
  float4 acc = make_float4(0.f, 0.f, 0.f, 0.f);

  for (int k0 = 0; k0 < DM; k0 += 64) {
    __syncthreads();
#pragma unroll
    for (int e = 0; e < 4; ++e) {
      int lin = tid + e * 256;
      int r = lin >> 4, cc = lin & 15;
      *(float4*)&Ws[r][cc * 4] = *(const float4*)(W + (size_t)(k0 + r) * DH + cc * 4);
    }
    *(float4*)&As[row][c4 * 4] = *(const float4*)(A + (size_t)(m0 + row) * DM + k0 + c4 * 4);
    __syncthreads();
#pragma unroll
    for (int kk = 0; kk < 64; ++kk) {
      float a = As[row][kk];
      float4 wv = *(const float4*)&Ws[kk][c4 * 4];
      acc.x += a * wv.x; acc.y += a * wv.y; acc.z += a * wv.z; acc.w += a * wv.w;
    }
  }
  *(float4*)(C + (size_t)(m0 + row) * DH + c4 * 4) = acc;
}

// ---------------------------------------------------------------------------
// ctx split-K partials + reduce
// ---------------------------------------------------------------------------
__global__ __launch_bounds__(256)
void ctx_part_kernel(const float* __restrict__ attn, const float* __restrict__ Vp,
                     float* __restrict__ part) {
  const int c = blockIdx.x, mt = blockIdx.y, b = blockIdx.z;
  const int tid = threadIdx.x;
  const int tx = tid & 15, ty = tid >> 4;
  __shared__ float As[64][68];
  __shared__ float Vs[64][68];
  const float* attn_b = attn + (size_t)b * T_SZ * T_SZ;
  const float* V_b = Vp + (size_t)b * T_SZ * DH;

  float acc[4][4] = {};
  const int kt_lo = c * 4;
  const int kt_hi = (mt < kt_lo + 3) ? mt : (kt_lo + 3);

  for (int kt = kt_lo; kt <= kt_hi; ++kt) {
    __syncthreads();
#pragma unroll
    for (int e = 0; e < 4; ++e) {
      int lin = tid + e * 256;
      int i = lin >> 4, c4 = lin & 15;
      *(float4*)&As[i][c4 * 4] =
          *(const float4*)(attn_b + (size_t)(mt * 64 + i) * T_SZ + kt * 64 + c4 * 4);
      *(float4*)&Vs[i][c4 * 4] =
          *(const float4*)(V_b + (size_t)(kt * 64 + i) * DH + c4 * 4);
    }
    __syncthreads();
#pragma unroll
    for (int kk = 0; kk < 64; kk += 4) {
      float4 a[4];
#pragma unroll
      for (int i = 0; i < 4; ++i) a[i] = *(const float4*)&As[ty * 4 + i][kk];
      float4 vr[4];
#pragma unroll
      for (int t = 0; t < 4; ++t) vr[t] = *(const float4*)&Vs[kk + t][tx * 4];
#pragma unroll
      for (int i = 0; i < 4; ++i) {
        float av[4] = {a[i].x, a[i].y, a[i].z, a[i].w};
#pragma unroll
        for (int t = 0; t < 4; ++t) {
          acc[i][0] += av[t] * vr[t].x;
          acc[i][1] += av[t] * vr[t].y;
          acc[i][2] += av[t] * vr[t].z;
          acc[i][3] += av[t] * vr[t].w;
        }
      }
    }
  }
  float* pp = part + (((size_t)c * B_SZ + b) * T_SZ + (size_t)mt * 64) * DH;
#pragma unroll
  for (int i = 0; i < 4; ++i)
    *(float4*)(pp + (size_t)(ty * 4 + i) * DH + tx * 4) =
        make_float4(acc[i][0], acc[i][1], acc[i][2], acc[i][3]);
}

__global__ __launch_bounds__(256)
void ctx_reduce(const float* __restrict__ part, float* __restrict__ ctx) {
  int i = blockIdx.x * 256 + threadIdx.x;
  float4 s = make_float4(0.f, 0.f, 0.f, 0.f);
#pragma unroll
  for (int c = 0; c < CTX_CH; ++c) {
    float4 p = ((const float4*)(part + (size_t)c * MROWS * DH))[i];
    s.x += p.x; s.y += p.y; s.z += p.z; s.w += p.w;
  }
  ((float4*)ctx)[i] = s;
}

// ---------------------------------------------------------------------------
// fp32 GEMM for the Wo projection (256 blocks).
// ---------------------------------------------------------------------------
__global__ __launch_bounds__(256)
void gemm128(const float* __restrict__ A, const float* __restrict__ W,
             float* __restrict__ C, int M, int N, int K) {
  __shared__ float As[16][132];
  __shared__ float Ws[16][132];
  const int tid = threadIdx.x;
  const int tx = tid & 15, ty = tid >> 4;
  const int n0 = blockIdx.x * 128;
  const int m0 = blockIdx.y * 128;

  float acc[8][8];
#pragma unroll
  for (int i = 0; i < 8; ++i)
#pragma unroll
    for (int j = 0; j < 8; ++j) acc[i][j] = 0.f;

  for (int k0 = 0; k0 < K; k0 += 16) {
#pragma unroll
    for (int e = 0; e < 2; ++e) {
      int lin = tid + e * 256;
      int i = lin >> 2, j4 = lin & 3;
      float4 av = *(const float4*)(A + (size_t)(m0 + i) * K + k0 + j4 * 4);
      As[j4 * 4 + 0][i] = av.x;
      As[j4 * 4 + 1][i] = av.y;
      As[j4 * 4 + 2][i] = av.z;
      As[j4 * 4 + 3][i] = av.w;
    }
#pragma unroll
    for (int e = 0; e < 2; ++e) {
      int lin = tid + e * 256;
      int kk = lin >> 5, n4 = lin & 31;
      int n = n0 + n4 * 4;
      float4 wv = make_float4(0.f, 0.f, 0.f, 0.f);
      if (n < N) wv = *(const float4*)(W + (size_t)(k0 + kk) * N + n);
      *(float4*)&Ws[kk][n4 * 4] = wv;
    }
    __syncthreads();
#pragma unroll
    for (int kk = 0; kk < 16; ++kk) {
      float4 a0 = *(const float4*)&As[kk][ty * 8];
      float4 a1 = *(const float4*)&As[kk][ty * 8 + 4];
      float4 b0 = *(const float4*)&Ws[kk][tx * 8];
      float4 b1 = *(const float4*)&Ws[kk][tx * 8 + 4];
      float a[8] = {a0.x, a0.y, a0.z, a0.w, a1.x, a1.y, a1.z, a1.w};
      float b[8] = {b0.x, b0.y, b0.z, b0.w, b1.x, b1.y, b1.z, b1.w};
#pragma unroll
      for (int i = 0; i < 8; ++i)
#pragma unroll
        for (int j = 0; j < 8; ++j) acc[i][j] += a[i] * b[j];
    }
    __syncthreads();
  }
#pragma unroll
  for (int i = 0; i < 8; ++i) {
    size_t m = (size_t)(m0 + ty * 8 + i);
    int n = n0 + tx * 8;
    if (n < N) *(float4*)(C + m * N + n) = make_float4(acc[i][0], acc[i][1], acc[i][2], acc[i][3]);
    if (n + 4 < N) *(float4*)(C + m * N + n + 4) = make_float4(acc[i][4], acc[i][5], acc[i][6], acc[i][7]);
  }
}

// ---------------------------------------------------------------------------
extern "C" void kernel_launch(void* const* d_in, const int* in_sizes, int n_in,
                              void* d_out, int out_size, void* d_ws, size_t ws_size,
                              hipStream_t stream) {
  (void)in_sizes; (void)n_in; (void)out_size; (void)ws_size;

  const float* q  = (const float*)d_in[0];
  const float* k  = (const float*)d_in[1];
  const float* v  = (const float*)d_in[2];
  // d_in[3] is the causal tril mask; causality applied analytically.
  const float* Wq = (const float*)d_in[4];
  const float* Wk = (const float*)d_in[5];
  const float* Wv = (const float*)d_in[6];
  const float* Wo = (const float*)d_in[7];

  float* out  = (float*)d_out;                      // [4096][1024]
  float* attn = out + (size_t)MROWS * DM;           // [2][2048][2048]

  // Workspace (~31.5 MB)
  u16*   Qb   = (u16*)d_ws;                         // [4096][1024] bf16 (Q pre-scaled by 0.125*log2e)
  u16*   Kb   = Qb + (size_t)MROWS * DM;
  u16*   Wqt  = Kb + (size_t)MROWS * DM;            // [1024][1024] bf16 (W^T)
  u16*   Wkt  = Wqt + (size_t)DM * DM;
  float* Vp   = (float*)(Wkt + (size_t)DM * DM);    // [4096][64] f32
  float* invL = Vp + (size_t)MROWS * DH;            // [2][16][2048] f32 (1/rowsum)
  float* ctx  = invL + (size_t)B_SZ * NH * T_SZ;    // [4096][64] f32
  float* part = ctx + (size_t)MROWS * DH;           // [8][4096][64] f32 (8.4 MB)

  // bf16 copies of q,k staged inside the attn output region (consumed by the
  // projection GEMMs before attn_write_v5 overwrites that region).
  u16* qb_in = (u16*)attn;
  u16* kb_in = qb_in + (size_t)MROWS * DM;

  dim3 thr(256, 1, 1);
  const int n4 = MROWS * DM / 4;

  k_cvt2<<<dim3(n4 / 256, 1, 2), thr, 0, stream>>>(q, k, qb_in, kb_in);
  k_cvt_T2<<<dim3(DM / 64, DM / 64, 2), thr, 0, stream>>>(Wq, Wk, Wqt, Wkt);

  // Q pre-scaled so prob = exp2(score): scale = 0.125 * log2(e)
  const float qscale = 0.125f * 1.44269504088896340736f;
  gemm_qk<<<dim3(DM / 128, MROWS / 128, 2), thr, 0, stream>>>(qb_in, kb_in, Wqt, Wkt, Qb, Kb, qscale);
  proj_v<<<MROWS / 16, thr, 0, stream>>>(v, Wv, Vp);

  attn_sums_v5<<<dim3(T_SZ / 64, NH, B_SZ), thr, 0, stream>>>(Qb, Kb, invL);
  attn_write_v5<<<dim3(T_SZ / 64, T_SZ / 64, B_SZ), thr, 0, stream>>>(Qb, Kb, invL, attn);

  ctx_part_kernel<<<dim3(CTX_CH, T_SZ / 64, B_SZ), thr, 0, stream>>>(attn, Vp, part);
  ctx_reduce<<<MROWS * DH / 4 / 256, thr, 0, stream>>>(part, ctx);
  gemm128<<<dim3(DM / 128, MROWS / 128), thr, 0, stream>>>(ctx, Wo, out, MROWS, DM, DH);
}

// Round 8
// 314.682 us; speedup vs baseline: 1.4011x; 1.4011x over previous
//
#include <hip/hip_runtime.h>

// Problem constants (fixed by the reference setup_inputs)
#define B_SZ 2
#define T_SZ 2048
#define DM   1024
#define NH   16
#define DH   64
#define MROWS (B_SZ * T_SZ)   // 4096
#define CTX_CH 8              // split-K chunks for the ctx matmul

typedef unsigned short u16;
typedef short  s16x8 __attribute__((ext_vector_type(8)));   // 8 bf16 (4 VGPRs)
typedef float  f32x4 __attribute__((ext_vector_type(4)));   // MFMA C/D

// fp32 -> bf16 round-to-nearest-even
static __device__ __forceinline__ u16 f2bf(float x) {
  unsigned u = __float_as_uint(x);
  u += 0x7fffu + ((u >> 16) & 1u);
  return (u16)(u >> 16);
}

// ---------------------------------------------------------------------------
// Wt[n][k] = bf16(W[k][n]) for Wq/Wk (z selects). grid (16,16,2).
// ---------------------------------------------------------------------------
__global__ __launch_bounds__(256)
void k_cvt_T2(const float* __restrict__ Wq, const float* __restrict__ Wk,
              u16* __restrict__ Wqt, u16* __restrict__ Wkt) {
  const float* W = blockIdx.z ? Wk : Wq;
  u16* Wt = blockIdx.z ? Wkt : Wqt;
  __shared__ u16 t[64][72];
  const int n0 = blockIdx.x * 64, k0 = blockIdx.y * 64;
  const int tid = threadIdx.x;
#pragma unroll
  for (int e = 0; e < 4; ++e) {
    int c = tid + e * 256;
    int k = c >> 4, n4 = c & 15;
    float4 v = *(const float4*)(W + (size_t)(k0 + k) * DM + n0 + n4 * 4);
    t[n4 * 4 + 0][k] = f2bf(v.x);
    t[n4 * 4 + 1][k] = f2bf(v.y);
    t[n4 * 4 + 2][k] = f2bf(v.z);
    t[n4 * 4 + 3][k] = f2bf(v.w);
  }
  __syncthreads();
#pragma unroll
  for (int e = 0; e < 2; ++e) {
    int c = tid + e * 256;
    int n = c >> 3, c16 = c & 7;
    *(uint4*)(Wt + (size_t)(n0 + n) * DM + k0 + c16 * 8) = *(const uint4*)&t[n][c16 * 8];
  }
}

// ---------------------------------------------------------------------------
// Merged projection GEMM with FUSED A-side f32->bf16 convert:
// z=0: Qp = (f32 q @ Wqt^T)*qscale, z=1: Kp = f32 k @ Wkt^T.
// 128x128 tile, BK=32, 4 waves 2x2. grid (8,32,2). A staged via transient
// float4 regs (no loop-carried prefetch arrays -> no scratch spill).
// ---------------------------------------------------------------------------
__global__ __launch_bounds__(256)
void gemm_qk(const float* __restrict__ qf, const float* __restrict__ kf,
             const u16* __restrict__ Wqt, const u16* __restrict__ Wkt,
             u16* __restrict__ Qp, u16* __restrict__ Kp, float qscale) {
  const int z = blockIdx.z;
  const float* A = z ? kf : qf;
  const u16* Bt = z ? Wkt : Wqt;
  u16* C = z ? Kp : Qp;
  const float scale = z ? 1.0f : qscale;

  __shared__ u16 As[128][40];
  __shared__ u16 Bs[128][40];
  const int tid = threadIdx.x;
  const int lane = tid & 63, w = tid >> 6;
  const int l15 = lane & 15, q4 = lane >> 4;
  const int wm = w & 1, wn = w >> 1;
  const int m0 = blockIdx.y * 128, n0 = blockIdx.x * 128;

  f32x4 acc[4][4] = {};

  for (int k0 = 0; k0 < DM; k0 += 32) {
    __syncthreads();
    // A tile: 128 rows x 32 k f32 -> bf16. 1024 float4, 4/thread, coalesced.
#pragma unroll
    for (int e = 0; e < 4; ++e) {
      int c = tid + e * 256;
      int row = c >> 3, c4 = c & 7;
      float4 av = *(const float4*)(A + (size_t)(m0 + row) * DM + k0 + c4 * 4);
      ushort4 o;
      o.x = f2bf(av.x); o.y = f2bf(av.y); o.z = f2bf(av.z); o.w = f2bf(av.w);
      *(ushort4*)&As[row][c4 * 4] = o;
    }
    // B tile: bf16, 512 uint4, 2/thread.
#pragma unroll
    for (int e = 0; e < 2; ++e) {
      int c = tid + e * 256;
      int row = c >> 2, c16 = c & 3;
      *(uint4*)&Bs[row][c16 * 8] = *(const uint4*)(Bt + (size_t)(n0 + row) * DM + k0 + c16 * 8);
    }
    __syncthreads();
    s16x8 a[4], b[4];
#pragma unroll
    for (int mi = 0; mi < 4; ++mi) a[mi] = *(const s16x8*)&As[wm * 64 + mi * 16 + l15][q4 * 8];
#pragma unroll
    for (int ni = 0; ni < 4; ++ni) b[ni] = *(const s16x8*)&Bs[wn * 64 + ni * 16 + l15][q4 * 8];
#pragma unroll
    for (int mi = 0; mi < 4; ++mi)
#pragma unroll
      for (int ni = 0; ni < 4; ++ni)
        acc[mi][ni] = __builtin_amdgcn_mfma_f32_16x16x32_bf16(a[mi], b[ni], acc[mi][ni], 0, 0, 0);
  }
#pragma unroll
  for (int mi = 0; mi < 4; ++mi)
#pragma unroll
    for (int ni = 0; ni < 4; ++ni)
#pragma unroll
      for (int r = 0; r < 4; ++r) {
        int m = m0 + wm * 64 + mi * 16 + q4 * 4 + r;
        int n = n0 + wn * 64 + ni * 16 + l15;
        C[(size_t)m * DM + n] = f2bf(acc[mi][ni][r] * scale);
      }
}

// ---------------------------------------------------------------------------
// Pass 1 (R5-proven): block (x,h,b) handles q-tiles x and 31-x (uniform 33
// chunks). Q frags in registers; K tile register-prefetch (2 uint4 only —
// small enough to stay in VGPRs). Q pre-scaled so prob = exp2(score).
// ---------------------------------------------------------------------------
__global__ __launch_bounds__(256)
void attn_sums_v2(const u16* __restrict__ Qb, const u16* __restrict__ Kb,
                  float* __restrict__ invL) {
  __shared__ u16 Ts[64][68];
  __shared__ float red[64][17];
  const int x = blockIdx.x, h = blockIdx.y, b = blockIdx.z;
  const int tid = threadIdx.x;
  const int lane = tid & 63, w = tid >> 6;
  const int l15 = lane & 15, q4 = lane >> 4;

  const int qts[2] = {x, 31 - x};
  s16x8 qf[2][2];
#pragma unroll
  for (int s = 0; s < 2; ++s) {
    const u16* Qbase = Qb + ((size_t)(b * T_SZ + qts[s] * 64)) * DM + h * DH;
    __syncthreads();
#pragma unroll
    for (int e = 0; e < 2; ++e) {
      int lin = tid + e * 256;
      int row = lin >> 3, c8 = lin & 7;
      *(uint4*)&Ts[row][c8 * 8] = *(const uint4*)(Qbase + (size_t)row * DM + c8 * 8);
    }
    __syncthreads();
    qf[s][0] = *(const s16x8*)&Ts[w * 16 + l15][q4 * 8];
    qf[s][1] = *(const s16x8*)&Ts[w * 16 + l15][32 + q4 * 8];
  }

  float part[2][4] = {};
  const int last = 31 - x;

  uint4 pf[2];
  {
    const u16* Kbase = Kb + ((size_t)(b * T_SZ)) * DM + h * DH;
#pragma unroll
    for (int e = 0; e < 2; ++e) {
      int lin = tid + e * 256;
      int row = lin >> 3, c8 = lin & 7;
      pf[e] = *(const uint4*)(Kbase + (size_t)row * DM + c8 * 8);
    }
  }

  for (int kt = 0; kt <= last; ++kt) {
    __syncthreads();
#pragma unroll
    for (int e = 0; e < 2; ++e) {
      int lin = tid + e * 256;
      int row = lin >> 3, c8 = lin & 7;
      *(uint4*)&Ts[row][c8 * 8] = pf[e];
    }
    if (kt < last) {
      const u16* Kbase = Kb + ((size_t)(b * T_SZ + (kt + 1) * 64)) * DM + h * DH;
#pragma unroll
      for (int e = 0; e < 2; ++e) {
        int lin = tid + e * 256;
        int row = lin >> 3, c8 = lin & 7;
        pf[e] = *(const uint4*)(Kbase + (size_t)row * DM + c8 * 8);
      }
    }
    __syncthreads();
    s16x8 bf0[4], bf1[4];
#pragma unroll
    for (int ni = 0; ni < 4; ++ni) {
      bf0[ni] = *(const s16x8*)&Ts[ni * 16 + l15][q4 * 8];
      bf1[ni] = *(const s16x8*)&Ts[ni * 16 + l15][32 + q4 * 8];
    }
#pragma unroll
    for (int s = 0; s < 2; ++s) {
      if (kt > qts[s]) continue;    // wave-uniform
      f32x4 sacc[4] = {};
#pragma unroll
      for (int ni = 0; ni < 4; ++ni) {
        sacc[ni] = __builtin_amdgcn_mfma_f32_16x16x32_bf16(qf[s][0], bf0[ni], sacc[ni], 0, 0, 0);
        sacc[ni] = __builtin_amdgcn_mfma_f32_16x16x32_bf16(qf[s][1], bf1[ni], sacc[ni], 0, 0, 0);
      }
      const bool diag = (kt == qts[s]);
#pragma unroll
      for (int ni = 0; ni < 4; ++ni)
#pragma unroll
        for (int r = 0; r < 4; ++r) {
          int row_l = w * 16 + q4 * 4 + r;
          int col_l = ni * 16 + l15;
          bool ok = !diag || (col_l <= row_l);
          part[s][r] += ok ? __builtin_amdgcn_exp2f(sacc[ni][r]) : 0.f;
        }
    }
  }

#pragma unroll
  for (int s = 0; s < 2; ++s) {
    __syncthreads();
#pragma unroll
    for (int r = 0; r < 4; ++r) red[w * 16 + q4 * 4 + r][l15] = part[s][r];
    __syncthreads();
    if (tid < 64) {
      float sum = 0.f;
#pragma unroll
      for (int t = 0; t < 16; ++t) sum += red[tid][t];
      invL[((size_t)(b * NH + h)) * T_SZ + qts[s] * 64 + tid] = 1.0f / sum;
    }
  }
}

// ---------------------------------------------------------------------------
// Pass 2 (R5-proven): block (c, qt, b) owns a 64(q) x 256(k) strip.
// Strips fully above diagonal zero-fill and exit. Per head: stage Q+K via
// transient regs (no persistent prefetch arrays), 32 MFMAs + 64 exps/wave.
// ---------------------------------------------------------------------------
__global__ __launch_bounds__(256)
void attn_write_v3(const u16* __restrict__ Qb, const u16* __restrict__ Kb,
                   const float* __restrict__ invL, float* __restrict__ attn) {
  const int c = blockIdx.x, qt = blockIdx.y, b = blockIdx.z;
  const int tid = threadIdx.x;
  float* outp = attn + ((size_t)b * T_SZ + (size_t)qt * 64) * T_SZ + c * 256;

  if (4 * c > qt) {            // whole strip above diagonal
    float4 z = make_float4(0.f, 0.f, 0.f, 0.f);
#pragma unroll
    for (int e = 0; e < 16; ++e) {
      int lin = tid + e * 256;
      int i = lin >> 6, c4 = lin & 63;
      *(float4*)(outp + (size_t)i * T_SZ + c4 * 4) = z;
    }
    return;
  }

  __shared__ u16 Qs[64][72];
  __shared__ u16 Ks[256][72];
  __shared__ float Ls[16][64];
  const int lane = tid & 63, w = tid >> 6;
  const int l15 = lane & 15, q4 = lane >> 4;

  {  // stage invL for all heads once
    int hh = tid >> 4, r4 = tid & 15;
    *(float4*)&Ls[hh][r4 * 4] =
        *(const float4*)(invL + ((size_t)(b * NH + hh)) * T_SZ + qt * 64 + r4 * 4);
  }

  const u16* Qrow = Qb + ((size_t)(b * T_SZ + qt * 64)) * DM;
  const u16* Krow = Kb + ((size_t)(b * T_SZ + c * 256)) * DM;

  f32x4 acc[4][4] = {};   // [ktl][ni]

  for (int h = 0; h < NH; ++h) {
    __syncthreads();
    const int hoff = h * DH;
#pragma unroll
    for (int e = 0; e < 2; ++e) {   // Q: 512 x 16B chunks
      int cc = tid + e * 256;
      int row = cc >> 3, c8 = cc & 7;
      *(uint4*)&Qs[row][c8 * 8] = *(const uint4*)(Qrow + (size_t)row * DM + hoff + c8 * 8);
    }
#pragma unroll
    for (int e = 0; e < 8; ++e) {   // K: 2048 x 16B chunks (4 tiles stacked)
      int cc = tid + e * 256;
      int row = cc >> 3, c8 = cc & 7;
      *(uint4*)&Ks[row][c8 * 8] = *(const uint4*)(Krow + (size_t)row * DM + hoff + c8 * 8);
    }
    __syncthreads();
    s16x8 aq0 = *(const s16x8*)&Qs[w * 16 + l15][q4 * 8];
    s16x8 aq1 = *(const s16x8*)&Qs[w * 16 + l15][32 + q4 * 8];
#pragma unroll
    for (int ktl = 0; ktl < 4; ++ktl) {
      const int kt = 4 * c + ktl;
      if (kt > qt) continue;        // uniform; acc stays zero -> writes zeros
      f32x4 s[4] = {};
#pragma unroll
      for (int ni = 0; ni < 4; ++ni) {
        s16x8 b0 = *(const s16x8*)&Ks[ktl * 64 + ni * 16 + l15][q4 * 8];
        s16x8 b1 = *(const s16x8*)&Ks[ktl * 64 + ni * 16 + l15][32 + q4 * 8];
        s[ni] = __builtin_amdgcn_mfma_f32_16x16x32_bf16(aq0, b0, s[ni], 0, 0, 0);
        s[ni] = __builtin_amdgcn_mfma_f32_16x16x32_bf16(aq1, b1, s[ni], 0, 0, 0);
      }
      if (kt == qt) {
#pragma unroll
        for (int ni = 0; ni < 4; ++ni)
#pragma unroll
          for (int r = 0; r < 4; ++r) {
            int row_l = w * 16 + q4 * 4 + r;
            int col_l = ni * 16 + l15;
            float ev = __builtin_amdgcn_exp2f(s[ni][r]) * Ls[h][row_l];
            if (col_l <= row_l) acc[ktl][ni][r] += ev;
          }
      } else {
#pragma unroll
        for (int ni = 0; ni < 4; ++ni)
#pragma unroll
          for (int r = 0; r < 4; ++r) {
            int row_l = w * 16 + q4 * 4 + r;
            acc[ktl][ni][r] += __builtin_amdgcn_exp2f(s[ni][r]) * Ls[h][row_l];
          }
      }
    }
  }
#pragma unroll
  for (int ktl = 0; ktl < 4; ++ktl)
#pragma unroll
    for (int ni = 0; ni < 4; ++ni)
#pragma unroll
      for (int r = 0; r < 4; ++r)
        outp[(size_t)(w * 16 + q4 * 4 + r) * T_SZ + ktl * 64 + ni * 16 + l15] =
            acc[ktl][ni][r] * 0.0625f;
}

// ---------------------------------------------------------------------------
// V projection: C[4096][64] = A[4096][1024] @ W[1024][64], fp32. 256 blocks.
// ---------------------------------------------------------------------------
__global__ __launch_bounds__(256)
void proj_v(const float* __restrict__ A, const float* __restrict__ W,
            float* __restrict__ C) {
  __shared__ float Ws[64][68];
  __shared__ float As[16][68];
  const int tid = threadIdx.x;
  const int m0 = blockIdx.x * 16;
  const int row = tid >> 4;
  const int c4  = tid & 15;
  float4 acc = make_float4(0.f, 0.f, 0.f, 0.f);

  for (int k0 = 0; k0 < DM; k0 += 64) {
    __syncthreads();
#pragma unroll
    for (int e = 0; e < 4; ++e) {
      int lin = tid + e * 256;
      int r = lin >> 4, cc = lin & 15;
      *(float4*)&Ws[r][cc * 4] = *(const float4*)(W + (size_t)(k0 + r) * DH + cc * 4);
    }
    *(float4*)&As[row][c4 * 4] = *(const float4*)(A + (size_t)(m0 + row) * DM + k0 + c4 * 4);
    __syncthreads();
#pragma unroll
    for (int kk = 0; kk < 64; ++kk) {
      float a = As[row][kk];
      float4 wv = *(const float4*)&Ws[kk][c4 * 4];
      acc.x += a * wv.x; acc.y += a * wv.y; acc.z += a * wv.z; acc.w += a * wv.w;
    }
  }
  *(float4*)(C + (size_t)(m0 + row) * DH + c4 * 4) = acc;
}

// ---------------------------------------------------------------------------
// ctx split-K partials (reduce is fused into gemm_wo)
// ---------------------------------------------------------------------------
__global__ __launch_bounds__(256)
void ctx_part_kernel(const float* __restrict__ attn, const float* __restrict__ Vp,
                     float* __restrict__ part) {
  const int c = blockIdx.x, mt = blockIdx.y, b = blockIdx.z;
  const int tid = threadIdx.x;
  const int tx = tid & 15, ty = tid >> 4;
  __shared__ float As[64][68];
  __shared__ float Vs[64][68];
  const float* attn_b = attn + (size_t)b * T_SZ * T_SZ;
  const float* V_b = Vp + (size_t)b * T_SZ * DH;

  float acc[4][4] = {};
  const int kt_lo = c * 4;
  const int kt_hi = (mt < kt_lo + 3) ? mt : (kt_lo + 3);

  for (int kt = kt_lo; kt <= kt_hi; ++kt) {
    __syncthreads();
#pragma unroll
    for (int e = 0; e < 4; ++e) {
      int lin = tid + e * 256;
      int i = lin >> 4, c4 = lin & 15;
      *(float4*)&As[i][c4 * 4] =
          *(const float4*)(attn_b + (size_t)(mt * 64 + i) * T_SZ + kt * 64 + c4 * 4);
      *(float4*)&Vs[i][c4 * 4] =
          *(const float4*)(V_b + (size_t)(kt * 64 + i) * DH + c4 * 4);
    }
    __syncthreads();
#pragma unroll
    for (int kk = 0; kk < 64; kk += 4) {
      float4 a[4];
#pragma unroll
      for (int i = 0; i < 4; ++i) a[i] = *(const float4*)&As[ty * 4 + i][kk];
      float4 vr[4];
#pragma unroll
      for (int t = 0; t < 4; ++t) vr[t] = *(const float4*)&Vs[kk + t][tx * 4];
#pragma unroll
      for (int i = 0; i < 4; ++i) {
        float av[4] = {a[i].x, a[i].y, a[i].z, a[i].w};
#pragma unroll
        for (int t = 0; t < 4; ++t) {
          acc[i][0] += av[t] * vr[t].x;
          acc[i][1] += av[t] * vr[t].y;
          acc[i][2] += av[t] * vr[t].z;
          acc[i][3] += av[t] * vr[t].w;
        }
      }
    }
  }
  float* pp = part + (((size_t)c * B_SZ + b) * T_SZ + (size_t)mt * 64) * DH;
#pragma unroll
  for (int i = 0; i < 4; ++i)
    *(float4*)(pp + (size_t)(ty * 4 + i) * DH + tx * 4) =
        make_float4(acc[i][0], acc[i][1], acc[i][2], acc[i][3]);
}

// ---------------------------------------------------------------------------
// Wo projection with FUSED split-K reduce: out[4096][1024] =
// (sum_c part[c])[4096][64] @ Wo[64][1024]. fp32, 128x128 tile, BK=16.
// grid (8,32).
// ---------------------------------------------------------------------------
__global__ __launch_bounds__(256)
void gemm_wo(const float* __restrict__ part, const float* __restrict__ W,
             float* __restrict__ C) {
  __shared__ float As[16][132];
  __shared__ float Ws[16][132];
  const int tid = threadIdx.x;
  const int tx = tid & 15, ty = tid >> 4;
  const int n0 = blockIdx.x * 128;
  const int m0 = blockIdx.y * 128;

  float acc[8][8];
#pragma unroll
  for (int i = 0; i < 8; ++i)
#pragma unroll
    for (int j = 0; j < 8; ++j) acc[i][j] = 0.f;

  for (int k0 = 0; k0 < DH; k0 += 16) {
    __syncthreads();
    // A tile = sum of 8 split-K partials, reduced during staging.
#pragma unroll
    for (int e = 0; e < 2; ++e) {
      int lin = tid + e * 256;
      int i = lin >> 2, j4 = lin & 3;
      float4 s = make_float4(0.f, 0.f, 0.f, 0.f);
#pragma unroll
      for (int cc = 0; cc < CTX_CH; ++cc) {
        float4 p = *(const float4*)(part + (size_t)cc * MROWS * DH +
                                    (size_t)(m0 + i) * DH + k0 + j4 * 4);
        s.x += p.x; s.y += p.y; s.z += p.z; s.w += p.w;
      }
      As[j4 * 4 + 0][i] = s.x;
      As[j4 * 4 + 1][i] = s.y;
      As[j4 * 4 + 2][i] = s.z;
      As[j4 * 4 + 3][i] = s.w;
    }
#pragma unroll
    for (int e = 0; e < 2; ++e) {
      int lin = tid + e * 256;
      int kk = lin >> 5, n4 = lin & 31;
      *(float4*)&Ws[kk][n4 * 4] = *(const float4*)(W + (size_t)(k0 + kk) * DM + n0 + n4 * 4);
    }
    __syncthreads();
#pragma unroll
    for (int kk = 0; kk < 16; ++kk) {
      float4 a0 = *(const float4*)&As[kk][ty * 8];
      float4 a1 = *(const float4*)&As[kk][ty * 8 + 4];
      float4 b0 = *(const float4*)&Ws[kk][tx * 8];
      float4 b1 = *(const float4*)&Ws[kk][tx * 8 + 4];
      float a[8] = {a0.x, a0.y, a0.z, a0.w, a1.x, a1.y, a1.z, a1.w};
      float b[8] = {b0.x, b0.y, b0.z, b0.w, b1.x, b1.y, b1.z, b1.w};
#pragma unroll
      for (int i = 0; i < 8; ++i)
#pragma unroll
        for (int j = 0; j < 8; ++j) acc[i][j] += a[i] * b[j];
    }
  }
#pragma unroll
  for (int i = 0; i < 8; ++i) {
    size_t m = (size_t)(m0 + ty * 8 + i);
    int n = n0 + tx * 8;
    *(float4*)(C + m * DM + n) = make_float4(acc[i][0], acc[i][1], acc[i][2], acc[i][3]);
    *(float4*)(C + m * DM + n + 4) = make_float4(acc[i][4], acc[i][5], acc[i][6], acc[i][7]);
  }
}

// ---------------------------------------------------------------------------
extern "C" void kernel_launch(void* const* d_in, const int* in_sizes, int n_in,
                              void* d_out, int out_size, void* d_ws, size_t ws_size,
                              hipStream_t stream) {
  (void)in_sizes; (void)n_in; (void)out_size; (void)ws_size;

  const float* q  = (const float*)d_in[0];
  const float* k  = (const float*)d_in[1];
  const float* v  = (const float*)d_in[2];
  // d_in[3] is the causal tril mask; causality applied analytically.
  const float* Wq = (const float*)d_in[4];
  const float* Wk = (const float*)d_in[5];
  const float* Wv = (const float*)d_in[6];
  const float* Wo = (const float*)d_in[7];

  float* out  = (float*)d_out;                      // [4096][1024]
  float* attn = out + (size_t)MROWS * DM;           // [2][2048][2048]

  // Workspace (~30.5 MB)
  u16*   Qb   = (u16*)d_ws;                         // [4096][1024] bf16 (Q pre-scaled by 0.125*log2e)
  u16*   Kb   = Qb + (size_t)MROWS * DM;
  u16*   Wqt  = Kb + (size_t)MROWS * DM;            // [1024][1024] bf16 (W^T)
  u16*   Wkt  = Wqt + (size_t)DM * DM;
  float* Vp   = (float*)(Wkt + (size_t)DM * DM);    // [4096][64] f32
  float* invL = Vp + (size_t)MROWS * DH;            // [2][16][2048] f32 (1/rowsum)
  float* part = invL + (size_t)B_SZ * NH * T_SZ;    // [8][4096][64] f32 (8.4 MB)

  dim3 thr(256, 1, 1);

  k_cvt_T2<<<dim3(DM / 64, DM / 64, 2), thr, 0, stream>>>(Wq, Wk, Wqt, Wkt);

  // Q pre-scaled so prob = exp2(score): scale = 0.125 * log2(e)
  const float qscale = 0.125f * 1.44269504088896340736f;
  gemm_qk<<<dim3(DM / 128, MROWS / 128, 2), thr, 0, stream>>>(q, k, Wqt, Wkt, Qb, Kb, qscale);
  proj_v<<<MROWS / 16, thr, 0, stream>>>(v, Wv, Vp);

  attn_sums_v2<<<dim3(16, NH, B_SZ), thr, 0, stream>>>(Qb, Kb, invL);
  attn_write_v3<<<dim3(8, 32, B_SZ), thr, 0, stream>>>(Qb, Kb, invL, attn);

  ctx_part_kernel<<<dim3(CTX_CH, T_SZ / 64, B_SZ), thr, 0, stream>>>(attn, Vp, part);
  gemm_wo<<<dim3(DM / 128, MROWS / 128), thr, 0, stream>>>(part, Wo, out);
}

// Round 9
// 286.799 us; speedup vs baseline: 1.5373x; 1.0972x over previous
//
#include <hip/hip_runtime.h>

// Problem constants (fixed by the reference setup_inputs)
#define B_SZ 2
#define T_SZ 2048
#define DM   1024
#define NH   16
#define DH   64
#define MROWS (B_SZ * T_SZ)   // 4096
#define CTX_CH 8              // split-K chunks for the ctx matmul

typedef unsigned short u16;
typedef short  s16x8 __attribute__((ext_vector_type(8)));   // 8 bf16 (4 VGPRs)
typedef float  f32x4 __attribute__((ext_vector_type(4)));   // MFMA C/D

// fp32 -> bf16 round-to-nearest-even
static __device__ __forceinline__ u16 f2bf(float x) {
  unsigned u = __float_as_uint(x);
  u += 0x7fffu + ((u >> 16) & 1u);
  return (u16)(u >> 16);
}

// ---------------------------------------------------------------------------
// Wt[n][k] = bf16(W[k][n]) for Wq/Wk (z selects). grid (16,16,2).
// ---------------------------------------------------------------------------
__global__ __launch_bounds__(256)
void k_cvt_T2(const float* __restrict__ Wq, const float* __restrict__ Wk,
              u16* __restrict__ Wqt, u16* __restrict__ Wkt) {
  const float* W = blockIdx.z ? Wk : Wq;
  u16* Wt = blockIdx.z ? Wkt : Wqt;
  __shared__ u16 t[64][72];
  const int n0 = blockIdx.x * 64, k0 = blockIdx.y * 64;
  const int tid = threadIdx.x;
#pragma unroll
  for (int e = 0; e < 4; ++e) {
    int c = tid + e * 256;
    int k = c >> 4, n4 = c & 15;
    float4 v = *(const float4*)(W + (size_t)(k0 + k) * DM + n0 + n4 * 4);
    t[n4 * 4 + 0][k] = f2bf(v.x);
    t[n4 * 4 + 1][k] = f2bf(v.y);
    t[n4 * 4 + 2][k] = f2bf(v.z);
    t[n4 * 4 + 3][k] = f2bf(v.w);
  }
  __syncthreads();
#pragma unroll
  for (int e = 0; e < 2; ++e) {
    int c = tid + e * 256;
    int n = c >> 3, c16 = c & 7;
    *(uint4*)(Wt + (size_t)(n0 + n) * DM + k0 + c16 * 8) = *(const uint4*)&t[n][c16 * 8];
  }
}

// ---------------------------------------------------------------------------
// Merged projection GEMM with fused A-side f32->bf16 convert.
// GRID (32 m, 8 n, 2 z): blocks sharing an A row-band have IDs m+32n ->
// ID%8 == m%8 -> same XCD -> A band served from that XCD's L2 (not 8x HBM).
// ---------------------------------------------------------------------------
__global__ __launch_bounds__(256)
void gemm_qk(const float* __restrict__ qf, const float* __restrict__ kf,
             const u16* __restrict__ Wqt, const u16* __restrict__ Wkt,
             u16* __restrict__ Qp, u16* __restrict__ Kp, float qscale) {
  const int z = blockIdx.z;
  const float* A = z ? kf : qf;
  const u16* Bt = z ? Wkt : Wqt;
  u16* C = z ? Kp : Qp;
  const float scale = z ? 1.0f : qscale;

  __shared__ u16 As[128][40];
  __shared__ u16 Bs[128][40];
  const int tid = threadIdx.x;
  const int lane = tid & 63, w = tid >> 6;
  const int l15 = lane & 15, q4 = lane >> 4;
  const int wm = w & 1, wn = w >> 1;
  const int m0 = blockIdx.x * 128, n0 = blockIdx.y * 128;   // x=m for XCD share

  f32x4 acc[4][4] = {};

  for (int k0 = 0; k0 < DM; k0 += 32) {
    __syncthreads();
    // A tile: 128 rows x 32 k f32 -> bf16. 1024 float4, 4/thread, coalesced.
#pragma unroll
    for (int e = 0; e < 4; ++e) {
      int c = tid + e * 256;
      int row = c >> 3, c4 = c & 7;
      float4 av = *(const float4*)(A + (size_t)(m0 + row) * DM + k0 + c4 * 4);
      ushort4 o;
      o.x = f2bf(av.x); o.y = f2bf(av.y); o.z = f2bf(av.z); o.w = f2bf(av.w);
      *(ushort4*)&As[row][c4 * 4] = o;
    }
    // B tile: bf16, 512 uint4, 2/thread.
#pragma unroll
    for (int e = 0; e < 2; ++e) {
      int c = tid + e * 256;
      int row = c >> 2, c16 = c & 3;
      *(uint4*)&Bs[row][c16 * 8] = *(const uint4*)(Bt + (size_t)(n0 + row) * DM + k0 + c16 * 8);
    }
    __syncthreads();
    s16x8 a[4], b[4];
#pragma unroll
    for (int mi = 0; mi < 4; ++mi) a[mi] = *(const s16x8*)&As[wm * 64 + mi * 16 + l15][q4 * 8];
#pragma unroll
    for (int ni = 0; ni < 4; ++ni) b[ni] = *(const s16x8*)&Bs[wn * 64 + ni * 16 + l15][q4 * 8];
#pragma unroll
    for (int mi = 0; mi < 4; ++mi)
#pragma unroll
      for (int ni = 0; ni < 4; ++ni)
        acc[mi][ni] = __builtin_amdgcn_mfma_f32_16x16x32_bf16(a[mi], b[ni], acc[mi][ni], 0, 0, 0);
  }
#pragma unroll
  for (int mi = 0; mi < 4; ++mi)
#pragma unroll
    for (int ni = 0; ni < 4; ++ni)
#pragma unroll
      for (int r = 0; r < 4; ++r) {
        int m = m0 + wm * 64 + mi * 16 + q4 * 4 + r;
        int n = n0 + wn * 64 + ni * 16 + l15;
        C[(size_t)m * DM + n] = f2bf(acc[mi][ni][r] * scale);
      }
}

// ---------------------------------------------------------------------------
// Pass 1 v6: block (x,h,b) handles q-tiles x and 31-x. Rounds of 128 k-cols
// (two 64-tiles per barrier-pair, ~17 rounds vs 33). K staged transiently
// (load->store immediately, attn_write_v3's proven no-spill pattern).
// Q pre-scaled so prob = exp2(score).
// ---------------------------------------------------------------------------
__global__ __launch_bounds__(256)
void attn_sums_v6(const u16* __restrict__ Qb, const u16* __restrict__ Kb,
                  float* __restrict__ invL) {
  __shared__ u16 Ks[128][72];
  __shared__ float red[64][17];
  const int x = blockIdx.x, h = blockIdx.y, b = blockIdx.z;
  const int tid = threadIdx.x;
  const int lane = tid & 63, w = tid >> 6;
  const int l15 = lane & 15, q4 = lane >> 4;

  const int qts[2] = {x, 31 - x};
  s16x8 qf[2][2];
#pragma unroll
  for (int s = 0; s < 2; ++s) {     // stage each Q tile via lower half of Ks
    const u16* Qbase = Qb + ((size_t)(b * T_SZ + qts[s] * 64)) * DM + h * DH;
    __syncthreads();
#pragma unroll
    for (int e = 0; e < 2; ++e) {
      int lin = tid + e * 256;
      int row = lin >> 3, c8 = lin & 7;
      *(uint4*)&Ks[row][c8 * 8] = *(const uint4*)(Qbase + (size_t)row * DM + c8 * 8);
    }
    __syncthreads();
    qf[s][0] = *(const s16x8*)&Ks[w * 16 + l15][q4 * 8];
    qf[s][1] = *(const s16x8*)&Ks[w * 16 + l15][32 + q4 * 8];
  }

  float part[2][4] = {};
  const int last = 31 - x;                 // last kt tile needed
  const int R = (last + 2) >> 1;           // rounds of two tiles

  const u16* Kbase = Kb + ((size_t)b * T_SZ) * DM + h * DH;

  for (int r = 0; r < R; ++r) {
    __syncthreads();
    // stage K rows [r*128, r*128+127] (transient regs; may over-read past
    // 'last' tile within the same b — rows exist, harmless)
#pragma unroll
    for (int e = 0; e < 4; ++e) {
      int lin = tid + e * 256;
      int row = lin >> 3, c8 = lin & 7;
      *(uint4*)&Ks[row][c8 * 8] =
          *(const uint4*)(Kbase + (size_t)(r * 128 + row) * DM + c8 * 8);
    }
    __syncthreads();
#pragma unroll
    for (int ktl = 0; ktl < 2; ++ktl) {
      const int kt = r * 2 + ktl;
      if (kt > last) continue;             // wave-uniform
#pragma unroll
      for (int s = 0; s < 2; ++s) {
        if (kt > qts[s]) continue;         // wave-uniform
        f32x4 sacc[4] = {};
#pragma unroll
        for (int ni = 0; ni < 4; ++ni) {
          s16x8 b0 = *(const s16x8*)&Ks[ktl * 64 + ni * 16 + l15][q4 * 8];
          s16x8 b1 = *(const s16x8*)&Ks[ktl * 64 + ni * 16 + l15][32 + q4 * 8];
          sacc[ni] = __builtin_amdgcn_mfma_f32_16x16x32_bf16(qf[s][0], b0, sacc[ni], 0, 0, 0);
          sacc[ni] = __builtin_amdgcn_mfma_f32_16x16x32_bf16(qf[s][1], b1, sacc[ni], 0, 0, 0);
        }
        const bool diag = (kt == qts[s]);
#pragma unroll
        for (int ni = 0; ni < 4; ++ni)
#pragma unroll
          for (int rr = 0; rr < 4; ++rr) {
            int row_l = w * 16 + q4 * 4 + rr;
            int col_l = ni * 16 + l15;
            bool ok = !diag || (col_l <= row_l);
            part[s][rr] += ok ? __builtin_amdgcn_exp2f(sacc[ni][rr]) : 0.f;
          }
      }
    }
  }

#pragma unroll
  for (int s = 0; s < 2; ++s) {
    __syncthreads();
#pragma unroll
    for (int rr = 0; rr < 4; ++rr) red[w * 16 + q4 * 4 + rr][l15] = part[s][rr];
    __syncthreads();
    if (tid < 64) {
      float sum = 0.f;
#pragma unroll
      for (int t = 0; t < 16; ++t) sum += red[tid][t];
      invL[((size_t)(b * NH + h)) * T_SZ + qts[s] * 64 + tid] = 1.0f / sum;
    }
  }
}

// ---------------------------------------------------------------------------
// Pass 2 (R5-proven): block (c, qt, b) owns a 64(q) x 256(k) strip.
// ---------------------------------------------------------------------------
__global__ __launch_bounds__(256)
void attn_write_v3(const u16* __restrict__ Qb, const u16* __restrict__ Kb,
                   const float* __restrict__ invL, float* __restrict__ attn) {
  const int c = blockIdx.x, qt = blockIdx.y, b = blockIdx.z;
  const int tid = threadIdx.x;
  float* outp = attn + ((size_t)b * T_SZ + (size_t)qt * 64) * T_SZ + c * 256;

  if (4 * c > qt) {            // whole strip above diagonal
    float4 z = make_float4(0.f, 0.f, 0.f, 0.f);
#pragma unroll
    for (int e = 0; e < 16; ++e) {
      int lin = tid + e * 256;
      int i = lin >> 6, c4 = lin & 63;
      *(float4*)(outp + (size_t)i * T_SZ + c4 * 4) = z;
    }
    return;
  }

  __shared__ u16 Qs[64][72];
  __shared__ u16 Ks[256][72];
  __shared__ float Ls[16][64];
  const int lane = tid & 63, w = tid >> 6;
  const int l15 = lane & 15, q4 = lane >> 4;

  {  // stage invL for all heads once
    int hh = tid >> 4, r4 = tid & 15;
    *(float4*)&Ls[hh][r4 * 4] =
        *(const float4*)(invL + ((size_t)(b * NH + hh)) * T_SZ + qt * 64 + r4 * 4);
  }

  const u16* Qrow = Qb + ((size_t)(b * T_SZ + qt * 64)) * DM;
  const u16* Krow = Kb + ((size_t)(b * T_SZ + c * 256)) * DM;

  f32x4 acc[4][4] = {};   // [ktl][ni]

  for (int h = 0; h < NH; ++h) {
    __syncthreads();
    const int hoff = h * DH;
#pragma unroll
    for (int e = 0; e < 2; ++e) {   // Q: 512 x 16B chunks
      int cc = tid + e * 256;
      int row = cc >> 3, c8 = cc & 7;
      *(uint4*)&Qs[row][c8 * 8] = *(const uint4*)(Qrow + (size_t)row * DM + hoff + c8 * 8);
    }
#pragma unroll
    for (int e = 0; e < 8; ++e) {   // K: 2048 x 16B chunks (4 tiles stacked)
      int cc = tid + e * 256;
      int row = cc >> 3, c8 = cc & 7;
      *(uint4*)&Ks[row][c8 * 8] = *(const uint4*)(Krow + (size_t)row * DM + hoff + c8 * 8);
    }
    __syncthreads();
    s16x8 aq0 = *(const s16x8*)&Qs[w * 16 + l15][q4 * 8];
    s16x8 aq1 = *(const s16x8*)&Qs[w * 16 + l15][32 + q4 * 8];
#pragma unroll
    for (int ktl = 0; ktl < 4; ++ktl) {
      const int kt = 4 * c + ktl;
      if (kt > qt) continue;        // uniform; acc stays zero -> writes zeros
      f32x4 s[4] = {};
#pragma unroll
      for (int ni = 0; ni < 4; ++ni) {
        s16x8 b0 = *(const s16x8*)&Ks[ktl * 64 + ni * 16 + l15][q4 * 8];
        s16x8 b1 = *(const s16x8*)&Ks[ktl * 64 + ni * 16 + l15][32 + q4 * 8];
        s[ni] = __builtin_amdgcn_mfma_f32_16x16x32_bf16(aq0, b0, s[ni], 0, 0, 0);
        s[ni] = __builtin_amdgcn_mfma_f32_16x16x32_bf16(aq1, b1, s[ni], 0, 0, 0);
      }
      if (kt == qt) {
#pragma unroll
        for (int ni = 0; ni < 4; ++ni)
#pragma unroll
          for (int r = 0; r < 4; ++r) {
            int row_l = w * 16 + q4 * 4 + r;
            int col_l = ni * 16 + l15;
            float ev = __builtin_amdgcn_exp2f(s[ni][r]) * Ls[h][row_l];
            if (col_l <= row_l) acc[ktl][ni][r] += ev;
          }
      } else {
#pragma unroll
        for (int ni = 0; ni < 4; ++ni)
#pragma unroll
          for (int r = 0; r < 4; ++r) {
            int row_l = w * 16 + q4 * 4 + r;
            acc[ktl][ni][r] += __builtin_amdgcn_exp2f(s[ni][r]) * Ls[h][row_l];
          }
      }
    }
  }
#pragma unroll
  for (int ktl = 0; ktl < 4; ++ktl)
#pragma unroll
    for (int ni = 0; ni < 4; ++ni)
#pragma unroll
      for (int r = 0; r < 4; ++r)
        outp[(size_t)(w * 16 + q4 * 4 + r) * T_SZ + ktl * 64 + ni * 16 + l15] =
            acc[ktl][ni][r] * 0.0625f;
}

// ---------------------------------------------------------------------------
// V projection: C[4096][64] = A[4096][1024] @ W[1024][64], fp32. 256 blocks.
// ---------------------------------------------------------------------------
__global__ __launch_bounds__(256)
void proj_v(const float* __restrict__ A, const float* __restrict__ W,
            float* __restrict__ C) {
  __shared__ float Ws[64][68];
  __shared__ float As[16][68];
  const int tid = threadIdx.x;
  const int m0 = blockIdx.x * 16;
  const int row = tid >> 4;
  const int c4  = tid & 15;
  float4 acc = make_float4(0.f, 0.f, 0.f, 0.f);

  for (int k0 = 0; k0 < DM; k0 += 64) {
    __syncthreads();
#pragma unroll
    for (int e = 0; e < 4; ++e) {
      int lin = tid + e * 256;
      int r = lin >> 4, cc = lin & 15;
      *(float4*)&Ws[r][cc * 4] = *(const float4*)(W + (size_t)(k0 + r) * DH + cc * 4);
    }
    *(float4*)&As[row][c4 * 4] = *(const float4*)(A + (size_t)(m0 + row) * DM + k0 + c4 * 4);
    __syncthreads();
#pragma unroll
    for (int kk = 0; kk < 64; ++kk) {
      float a = As[row][kk];
      float4 wv = *(const float4*)&Ws[kk][c4 * 4];
      acc.x += a * wv.x; acc.y += a * wv.y; acc.z += a * wv.z; acc.w += a * wv.w;
    }
  }
  *(float4*)(C + (size_t)(m0 + row) * DH + c4 * 4) = acc;
}

// ---------------------------------------------------------------------------
// ctx split-K partials (reduce is fused into gemm_wo)
// ---------------------------------------------------------------------------
__global__ __launch_bounds__(256)
void ctx_part_kernel(const float* __restrict__ attn, const float* __restrict__ Vp,
                     float* __restrict__ part) {
  const int c = blockIdx.x, mt = blockIdx.y, b = blockIdx.z;
  const int tid = threadIdx.x;
  const int tx = tid & 15, ty = tid >> 4;
  __shared__ float As[64][68];
  __shared__ float Vs[64][68];
  const float* attn_b = attn + (size_t)b * T_SZ * T_SZ;
  const float* V_b = Vp + (size_t)b * T_SZ * DH;

  float acc[4][4] = {};
  const int kt_lo = c * 4;
  const int kt_hi = (mt < kt_lo + 3) ? mt : (kt_lo + 3);

  for (int kt = kt_lo; kt <= kt_hi; ++kt) {
    __syncthreads();
#pragma unroll
    for (int e = 0; e < 4; ++e) {
      int lin = tid + e * 256;
      int i = lin >> 4, c4 = lin & 15;
      *(float4*)&As[i][c4 * 4] =
          *(const float4*)(attn_b + (size_t)(mt * 64 + i) * T_SZ + kt * 64 + c4 * 4);
      *(float4*)&Vs[i][c4 * 4] =
          *(const float4*)(V_b + (size_t)(kt * 64 + i) * DH + c4 * 4);
    }
    __syncthreads();
#pragma unroll
    for (int kk = 0; kk < 64; kk += 4) {
      float4 a[4];
#pragma unroll
      for (int i = 0; i < 4; ++i) a[i] = *(const float4*)&As[ty * 4 + i][kk];
      float4 vr[4];
#pragma unroll
      for (int t = 0; t < 4; ++t) vr[t] = *(const float4*)&Vs[kk + t][tx * 4];
#pragma unroll
      for (int i = 0; i < 4; ++i) {
        float av[4] = {a[i].x, a[i].y, a[i].z, a[i].w};
#pragma unroll
        for (int t = 0; t < 4; ++t) {
          acc[i][0] += av[t] * vr[t].x;
          acc[i][1] += av[t] * vr[t].y;
          acc[i][2] += av[t] * vr[t].z;
          acc[i][3] += av[t] * vr[t].w;
        }
      }
    }
  }
  float* pp = part + (((size_t)c * B_SZ + b) * T_SZ + (size_t)mt * 64) * DH;
#pragma unroll
  for (int i = 0; i < 4; ++i)
    *(float4*)(pp + (size_t)(ty * 4 + i) * DH + tx * 4) =
        make_float4(acc[i][0], acc[i][1], acc[i][2], acc[i][3]);
}

// ---------------------------------------------------------------------------
// Wo projection with fused split-K reduce. GRID (32 m, 8 n): blocks sharing
// the reduced A-band land on the same XCD (ID%8 == m%8) -> part re-reads
// served from L2, not HBM.
// ---------------------------------------------------------------------------
__global__ __launch_bounds__(256)
void gemm_wo(const float* __restrict__ part, const float* __restrict__ W,
             float* __restrict__ C) {
  __shared__ float As[16][132];
  __shared__ float Ws[16][132];
  const int tid = threadIdx.x;
  const int tx = tid & 15, ty = tid >> 4;
  const int m0 = blockIdx.x * 128;   // x=m for XCD share
  const int n0 = blockIdx.y * 128;

  float acc[8][8];
#pragma unroll
  for (int i = 0; i < 8; ++i)
#pragma unroll
    for (int j = 0; j < 8; ++j) acc[i][j] = 0.f;

  for (int k0 = 0; k0 < DH; k0 += 16) {
    __syncthreads();
    // A tile = sum of 8 split-K partials, reduced during staging.
#pragma unroll
    for (int e = 0; e < 2; ++e) {
      int lin = tid + e * 256;
      int i = lin >> 2, j4 = lin & 3;
      float4 s = make_float4(0.f, 0.f, 0.f, 0.f);
#pragma unroll
      for (int cc = 0; cc < CTX_CH; ++cc) {
        float4 p = *(const float4*)(part + (size_t)cc * MROWS * DH +
                                    (size_t)(m0 + i) * DH + k0 + j4 * 4);
        s.x += p.x; s.y += p.y; s.z += p.z; s.w += p.w;
      }
      As[j4 * 4 + 0][i] = s.x;
      As[j4 * 4 + 1][i] = s.y;
      As[j4 * 4 + 2][i] = s.z;
      As[j4 * 4 + 3][i] = s.w;
    }
#pragma unroll
    for (int e = 0; e < 2; ++e) {
      int lin = tid + e * 256;
      int kk = lin >> 5, n4 = lin & 31;
      *(float4*)&Ws[kk][n4 * 4] = *(const float4*)(W + (size_t)(k0 + kk) * DM + n0 + n4 * 4);
    }
    __syncthreads();
#pragma unroll
    for (int kk = 0; kk < 16; ++kk) {
      float4 a0 = *(const float4*)&As[kk][ty * 8];
      float4 a1 = *(const float4*)&As[kk][ty * 8 + 4];
      float4 b0 = *(const float4*)&Ws[kk][tx * 8];
      float4 b1 = *(const float4*)&Ws[kk][tx * 8 + 4];
      float a[8] = {a0.x, a0.y, a0.z, a0.w, a1.x, a1.y, a1.z, a1.w};
      float b[8] = {b0.x, b0.y, b0.z, b0.w, b1.x, b1.y, b1.z, b1.w};
#pragma unroll
      for (int i = 0; i < 8; ++i)
#pragma unroll
        for (int j = 0; j < 8; ++j) acc[i][j] += a[i] * b[j];
    }
  }
#pragma unroll
  for (int i = 0; i < 8; ++i) {
    size_t m = (size_t)(m0 + ty * 8 + i);
    int n = n0 + tx * 8;
    *(float4*)(C + m * DM + n) = make_float4(acc[i][0], acc[i][1], acc[i][2], acc[i][3]);
    *(float4*)(C + m * DM + n + 4) = make_float4(acc[i][4], acc[i][5], acc[i][6], acc[i][7]);
  }
}

// ---------------------------------------------------------------------------
extern "C" void kernel_launch(void* const* d_in, const int* in_sizes, int n_in,
                              void* d_out, int out_size, void* d_ws, size_t ws_size,
                              hipStream_t stream) {
  (void)in_sizes; (void)n_in; (void)out_size; (void)ws_size;

  const float* q  = (const float*)d_in[0];
  const float* k  = (const float*)d_in[1];
  const float* v  = (const float*)d_in[2];
  // d_in[3] is the causal tril mask; causality applied analytically.
  const float* Wq = (const float*)d_in[4];
  const float* Wk = (const float*)d_in[5];
  const float* Wv = (const float*)d_in[6];
  const float* Wo = (const float*)d_in[7];

  float* out  = (float*)d_out;                      // [4096][1024]
  float* attn = out + (size_t)MROWS * DM;           // [2][2048][2048]

  // Workspace (~30.5 MB)
  u16*   Qb   = (u16*)d_ws;                         // [4096][1024] bf16 (Q pre-scaled by 0.125*log2e)
  u16*   Kb   = Qb + (size_t)MROWS * DM;
  u16*   Wqt  = Kb + (size_t)MROWS * DM;            // [1024][1024] bf16 (W^T)
  u16*   Wkt  = Wqt + (size_t)DM * DM;
  float* Vp   = (float*)(Wkt + (size_t)DM * DM);    // [4096][64] f32
  float* invL = Vp + (size_t)MROWS * DH;            // [2][16][2048] f32 (1/rowsum)
  float* part = invL + (size_t)B_SZ * NH * T_SZ;    // [8][4096][64] f32 (8.4 MB)

  dim3 thr(256, 1, 1);

  k_cvt_T2<<<dim3(DM / 64, DM / 64, 2), thr, 0, stream>>>(Wq, Wk, Wqt, Wkt);

  // Q pre-scaled so prob = exp2(score): scale = 0.125 * log2(e)
  const float qscale = 0.125f * 1.44269504088896340736f;
  gemm_qk<<<dim3(MROWS / 128, DM / 128, 2), thr, 0, stream>>>(q, k, Wqt, Wkt, Qb, Kb, qscale);
  proj_v<<<MROWS / 16, thr, 0, stream>>>(v, Wv, Vp);

  attn_sums_v6<<<dim3(16, NH, B_SZ), thr, 0, stream>>>(Qb, Kb, invL);
  attn_write_v3<<<dim3(8, 32, B_SZ), thr, 0, stream>>>(Qb, Kb, invL, attn);

  ctx_part_kernel<<<dim3(CTX_CH, T_SZ / 64, B_SZ), thr, 0, stream>>>(attn, Vp, part);
  gemm_wo<<<dim3(MROWS / 128, DM / 128), thr, 0, stream>>>(part, Wo, out);
}